// Round 1
// baseline (1708.308 us; speedup 1.0000x reference)
//
#include <hip/hip_runtime.h>
#include <hip/hip_bf16.h>

#define NPIX 2304
#define C_IN 256
#define NHEADS 8
#define DHEAD 32

// ---------------------------------------------------------------------------
// Kernel A: qkv[b][o][n] = sum_c Wqkv[o][c] * x[b][c][n] + bqkv[o]
// channel decomposition (from reshape(b, d, 3, m, n)): o = d*24 + k*8 + m
// scatter:  q -> [b][h][d][n]   (pre-scaled by 1/sqrt(32))
//           k -> [b][h][n][d]
//           v -> [b][h][n][d]
// 64x64 tile per block, 256 threads, 4x4 micro-tile per thread, BK=16.
// ---------------------------------------------------------------------------
__global__ __launch_bounds__(256) void qkv_gemm(
    const float* __restrict__ x, const float* __restrict__ W,
    const float* __restrict__ bias, float* __restrict__ qo,
    float* __restrict__ ko, float* __restrict__ vo)
{
    __shared__ float sW[16][68];   // sW[kj][oi]
    __shared__ float sX[16][68];   // sX[kj][ni]
    const int b     = blockIdx.z;
    const int oBase = blockIdx.y * 64;
    const int nBase = blockIdx.x * 64;
    const int t = threadIdx.x;
    const int r = t >> 4;          // 0..15 (output-row group)
    const int c = t & 15;          // 0..15 (output-col group)
    float acc[4][4] = {};
    const float* xb = x + (size_t)b * C_IN * NPIX;

    for (int kk = 0; kk < C_IN; kk += 16) {
        // stage W tile: sW[kj][oi] = W[oBase+oi][kk+kj]
        {
            const int oi = t >> 2;
            const int kj = (t & 3) * 4;
            float4 w4 = *(const float4*)&W[(oBase + oi) * C_IN + kk + kj];
            sW[kj + 0][oi] = w4.x;
            sW[kj + 1][oi] = w4.y;
            sW[kj + 2][oi] = w4.z;
            sW[kj + 3][oi] = w4.w;
            // stage X tile: sX[kj2][ni..ni+3]
            const int kj2 = t >> 4;
            const int ni  = (t & 15) * 4;
            float4 x4 = *(const float4*)&xb[(kk + kj2) * NPIX + nBase + ni];
            *(float4*)&sX[kj2][ni] = x4;
        }
        __syncthreads();
        #pragma unroll
        for (int kj = 0; kj < 16; ++kj) {
            float4 a4 = *(const float4*)&sW[kj][r * 4];
            float4 b4 = *(const float4*)&sX[kj][c * 4];
            float av[4] = {a4.x, a4.y, a4.z, a4.w};
            float bv[4] = {b4.x, b4.y, b4.z, b4.w};
            #pragma unroll
            for (int i = 0; i < 4; ++i)
                #pragma unroll
                for (int j = 0; j < 4; ++j)
                    acc[i][j] += av[i] * bv[j];
        }
        __syncthreads();
    }

    const float scale = 0.17677669529663687f;  // 32^-0.5
    #pragma unroll
    for (int i = 0; i < 4; ++i) {
        const int o = oBase + r * 4 + i;
        const float bi = bias[o];
        const int d   = o / 24;
        const int rem = o - d * 24;
        const int kq  = rem >> 3;
        const int h   = rem & 7;
        #pragma unroll
        for (int j = 0; j < 4; ++j) {
            const int n = nBase + c * 4 + j;
            const float val = acc[i][j] + bi;
            if (kq == 0)
                qo[((size_t)(b * NHEADS + h) * DHEAD + d) * NPIX + n] = val * scale;
            else if (kq == 1)
                ko[((size_t)(b * NHEADS + h) * NPIX + n) * DHEAD + d] = val;
            else
                vo[((size_t)(b * NHEADS + h) * NPIX + n) * DHEAD + d] = val;
        }
    }
}

// ---------------------------------------------------------------------------
// Kernel B: attention, one query per lane, online softmax.
// q: [b][h][d][n] (pre-scaled), k/v: [b][h][n][d]
// K/V rows are wave-uniform -> scalar loads; no LDS needed.
// output ao: [b][m*32+d][n]  (== input layout of final GEMM)
// ---------------------------------------------------------------------------
__global__ __launch_bounds__(64) void attn_kernel(
    const float* __restrict__ q, const float* __restrict__ k,
    const float* __restrict__ v, float* __restrict__ ao)
{
    const int bh = blockIdx.y;                       // 0..31
    const int qi = blockIdx.x * 64 + threadIdx.x;    // 0..2303
    const float* qb = q + (size_t)bh * DHEAD * NPIX;
    const float* Kb = k + (size_t)bh * NPIX * DHEAD;
    const float* Vb = v + (size_t)bh * NPIX * DHEAD;

    float qr[DHEAD];
    #pragma unroll
    for (int d = 0; d < DHEAD; ++d) qr[d] = qb[d * NPIX + qi];

    float mval = -3.0e38f, l = 0.f;
    float acc[DHEAD];
    #pragma unroll
    for (int d = 0; d < DHEAD; ++d) acc[d] = 0.f;

    for (int j = 0; j < NPIX; ++j) {
        const float* kr = Kb + j * DHEAD;   // uniform address -> s_load
        float s = 0.f;
        #pragma unroll
        for (int d = 0; d < DHEAD; ++d) s += qr[d] * kr[d];
        if (s > mval) {
            const float corr = __expf(mval - s);
            l *= corr;
            #pragma unroll
            for (int d = 0; d < DHEAD; ++d) acc[d] *= corr;
            mval = s;
        }
        const float p = __expf(s - mval);
        l += p;
        const float* vr = Vb + j * DHEAD;   // uniform address -> s_load
        #pragma unroll
        for (int d = 0; d < DHEAD; ++d) acc[d] += p * vr[d];
    }

    const float inv = 1.0f / l;
    float* aob = ao + (size_t)bh * DHEAD * NPIX + qi;
    #pragma unroll
    for (int d = 0; d < DHEAD; ++d) aob[d * NPIX] = acc[d] * inv;
}

// ---------------------------------------------------------------------------
// Kernel C: out[b][o][n] = sum_c W0[o][c] * ao[b][c][n] + b0[o]
// Same GEMM structure as kernel A, plain float4 epilogue.
// ---------------------------------------------------------------------------
__global__ __launch_bounds__(256) void out_gemm(
    const float* __restrict__ ain, const float* __restrict__ W,
    const float* __restrict__ bias, float* __restrict__ out)
{
    __shared__ float sW[16][68];
    __shared__ float sX[16][68];
    const int b     = blockIdx.z;
    const int oBase = blockIdx.y * 64;
    const int nBase = blockIdx.x * 64;
    const int t = threadIdx.x;
    const int r = t >> 4;
    const int c = t & 15;
    float acc[4][4] = {};
    const float* xb = ain + (size_t)b * C_IN * NPIX;

    for (int kk = 0; kk < C_IN; kk += 16) {
        {
            const int oi = t >> 2;
            const int kj = (t & 3) * 4;
            float4 w4 = *(const float4*)&W[(oBase + oi) * C_IN + kk + kj];
            sW[kj + 0][oi] = w4.x;
            sW[kj + 1][oi] = w4.y;
            sW[kj + 2][oi] = w4.z;
            sW[kj + 3][oi] = w4.w;
            const int kj2 = t >> 4;
            const int ni  = (t & 15) * 4;
            float4 x4 = *(const float4*)&xb[(kk + kj2) * NPIX + nBase + ni];
            *(float4*)&sX[kj2][ni] = x4;
        }
        __syncthreads();
        #pragma unroll
        for (int kj = 0; kj < 16; ++kj) {
            float4 a4 = *(const float4*)&sW[kj][r * 4];
            float4 b4 = *(const float4*)&sX[kj][c * 4];
            float av[4] = {a4.x, a4.y, a4.z, a4.w};
            float bv[4] = {b4.x, b4.y, b4.z, b4.w};
            #pragma unroll
            for (int i = 0; i < 4; ++i)
                #pragma unroll
                for (int j = 0; j < 4; ++j)
                    acc[i][j] += av[i] * bv[j];
        }
        __syncthreads();
    }

    #pragma unroll
    for (int i = 0; i < 4; ++i) {
        const int o = oBase + r * 4 + i;
        const float bi = bias[o];
        float4 st;
        st.x = acc[i][0] + bi;
        st.y = acc[i][1] + bi;
        st.z = acc[i][2] + bi;
        st.w = acc[i][3] + bi;
        *(float4*)&out[((size_t)b * C_IN + o) * NPIX + nBase + c * 4] = st;
    }
}

extern "C" void kernel_launch(void* const* d_in, const int* in_sizes, int n_in,
                              void* d_out, int out_size, void* d_ws, size_t ws_size,
                              hipStream_t stream) {
    const float* x    = (const float*)d_in[0];
    const float* Wqkv = (const float*)d_in[1];
    const float* bqkv = (const float*)d_in[2];
    const float* W0   = (const float*)d_in[3];
    const float* b0   = (const float*)d_in[4];
    float* out = (float*)d_out;

    const size_t per = (size_t)4 * NHEADS * DHEAD * NPIX;  // 2,359,296 floats
    float* qw = (float*)d_ws;
    float* kw = qw + per;
    float* vw = kw + per;
    float* aw = vw + per;

    qkv_gemm<<<dim3(NPIX / 64, 768 / 64, 4), 256, 0, stream>>>(x, Wqkv, bqkv, qw, kw, vw);
    attn_kernel<<<dim3(NPIX / 64, 32), 64, 0, stream>>>(qw, kw, vw, aw);
    out_gemm<<<dim3(NPIX / 64, C_IN / 64, 4), 256, 0, stream>>>(aw, W0, b0, out);
}

// Round 2
// 291.274 us; speedup vs baseline: 5.8650x; 5.8650x over previous
//
#include <hip/hip_runtime.h>
#include <hip/hip_bf16.h>

#define NPIX 2304
#define C_IN 256
#define NHEADS 8
#define DHEAD 32

typedef float f32x4 __attribute__((ext_vector_type(4)));
typedef __bf16 bf16x8 __attribute__((ext_vector_type(8)));

// ---------------------------------------------------------------------------
// Kernel A: qkv[b][o][n] = sum_c Wqkv[o][c] * x[b][c][n] + bqkv[o]
// Plain fp32 store; channel decode happens in the attention kernel.
// ---------------------------------------------------------------------------
__global__ __launch_bounds__(256) void qkv_gemm(
    const float* __restrict__ x, const float* __restrict__ W,
    const float* __restrict__ bias, float* __restrict__ qkv)
{
    __shared__ float sW[16][68];
    __shared__ float sX[16][68];
    const int b     = blockIdx.z;
    const int oBase = blockIdx.y * 64;
    const int nBase = blockIdx.x * 64;
    const int t = threadIdx.x;
    const int r = t >> 4;
    const int c = t & 15;
    float acc[4][4] = {};
    const float* xb = x + (size_t)b * C_IN * NPIX;

    for (int kk = 0; kk < C_IN; kk += 16) {
        {
            const int oi = t >> 2;
            const int kj = (t & 3) * 4;
            float4 w4 = *(const float4*)&W[(oBase + oi) * C_IN + kk + kj];
            sW[kj + 0][oi] = w4.x;
            sW[kj + 1][oi] = w4.y;
            sW[kj + 2][oi] = w4.z;
            sW[kj + 3][oi] = w4.w;
            const int kj2 = t >> 4;
            const int ni  = (t & 15) * 4;
            float4 x4 = *(const float4*)&xb[(kk + kj2) * NPIX + nBase + ni];
            *(float4*)&sX[kj2][ni] = x4;
        }
        __syncthreads();
        #pragma unroll
        for (int kj = 0; kj < 16; ++kj) {
            float4 a4 = *(const float4*)&sW[kj][r * 4];
            float4 b4 = *(const float4*)&sX[kj][c * 4];
            float av[4] = {a4.x, a4.y, a4.z, a4.w};
            float bv[4] = {b4.x, b4.y, b4.z, b4.w};
            #pragma unroll
            for (int i = 0; i < 4; ++i)
                #pragma unroll
                for (int j = 0; j < 4; ++j)
                    acc[i][j] += av[i] * bv[j];
        }
        __syncthreads();
    }

    #pragma unroll
    for (int i = 0; i < 4; ++i) {
        const int o = oBase + r * 4 + i;
        const float bi = bias[o];
        float4 st;
        st.x = acc[i][0] + bi;
        st.y = acc[i][1] + bi;
        st.z = acc[i][2] + bi;
        st.w = acc[i][3] + bi;
        *(float4*)&qkv[((size_t)b * 768 + o) * NPIX + nBase + c * 4] = st;
    }
}

// ---------------------------------------------------------------------------
// Kernel B: MFMA flash attention.
// qkv fp32 [b][768][2304], o = d*24 + kq*8 + h (kq: 0=q,1=k,2=v).
// Block: 256 thr = 4 waves, 64 Q-rows (16/wave); KV-tiles of 64 keys.
// Q,K hi/lo bf16 split (3 MFMAs -> ~fp32 scores); P,V single bf16.
// LDS: sKhi[64][32] / sKlo (rot-swizzled 16B chunks), sVt[32][64], sP[4][16][64].
// Output aw fp32 [b][h*32+d][n].
// ---------------------------------------------------------------------------
__global__ __launch_bounds__(256) void attn_mfma(
    const float* __restrict__ qkv, float* __restrict__ aw)
{
    __shared__ alignas(16) unsigned char sm[20480];
    const int tid = threadIdx.x;
    const int l = tid & 63;
    const int w = tid >> 6;
    const int g = l >> 4;          // 16-lane group within wave
    const int c16 = l & 15;

    // XCD-aware bijective swizzle: all 36 q-tiles of one bh on one XCD
    const int id = blockIdx.x;
    const int qt = id >> 5;                  // 0..35
    const int r5 = id & 31;
    const int bh = (r5 & 7) * 4 + (r5 >> 3); // 4 bh per XCD
    const int b = bh >> 3, h = bh & 7;
    const size_t qkvb = (size_t)b * 768 * NPIX;
    const int qbase = qt * 64;

    // ---- load Q fragment (row c16 of this wave's 16 rows), scaled, split ----
    const int qi = qbase + w * 16 + c16;
    bf16x8 qhi, qlo;
    #pragma unroll
    for (int e = 0; e < 8; ++e) {
        const int d = g * 8 + e;
        float v = qkv[qkvb + (size_t)(d * 24 + h) * NPIX + qi] * 0.17677669529663687f;
        __bf16 hb = (__bf16)v;
        qhi[e] = hb;
        qlo[e] = (__bf16)(v - (float)hb);
    }

    f32x4 o0 = {0.f, 0.f, 0.f, 0.f}, o1 = {0.f, 0.f, 0.f, 0.f};
    float mrow[4] = {-3e38f, -3e38f, -3e38f, -3e38f};
    float lrow[4] = {0.f, 0.f, 0.f, 0.f};

    const int vd = tid >> 3;   // V staging: d row 0..31
    const int vkc = tid & 7;   // V staging: 8-key chunk

    for (int kb = 0; kb < 36; ++kb) {
        const int j0 = kb * 64;
        __syncthreads();   // previous tile fully consumed

        // ---- stage K (hi+lo) : thread owns key j0+l, d-chunk w ----
        {
            float kv[8];
            #pragma unroll
            for (int e = 0; e < 8; ++e)
                kv[e] = qkv[qkvb + (size_t)((w * 8 + e) * 24 + 8 + h) * NPIX + j0 + l];
            bf16x8 kh8, kl8;
            #pragma unroll
            for (int e = 0; e < 8; ++e) {
                __bf16 hb = (__bf16)kv[e];
                kh8[e] = hb;
                kl8[e] = (__bf16)(kv[e] - (float)hb);
            }
            const int koff = l * 64 + ((w + (l >> 2)) & 3) * 16;
            *(bf16x8*)(sm + koff) = kh8;
            *(bf16x8*)(sm + 4096 + koff) = kl8;

            // ---- stage V^T : thread owns d=vd, keys vkc*8..+7 ----
            const float* vsrc = &qkv[qkvb + (size_t)(vd * 24 + 16 + h) * NPIX + j0 + vkc * 8];
            float vv[8];
            *(float4*)&vv[0] = *(const float4*)&vsrc[0];
            *(float4*)&vv[4] = *(const float4*)&vsrc[4];
            bf16x8 v8;
            #pragma unroll
            for (int e = 0; e < 8; ++e) v8[e] = (__bf16)vv[e];
            *(bf16x8*)(sm + 8192 + vd * 128 + ((vkc + vd) & 7) * 16) = v8;
        }
        __syncthreads();

        // ---- S = Q K^T (hi/lo split: qlo*khi + qhi*klo + qhi*khi) ----
        f32x4 s[4];
        #pragma unroll
        for (int f = 0; f < 4; ++f) {
            const int key = c16 + 16 * f;
            const int ko = key * 64 + ((g + (key >> 2)) & 3) * 16;
            bf16x8 kh = *(bf16x8*)(sm + ko);
            bf16x8 kl = *(bf16x8*)(sm + 4096 + ko);
            f32x4 acc = {0.f, 0.f, 0.f, 0.f};
            acc = __builtin_amdgcn_mfma_f32_16x16x32_bf16(qlo, kh, acc, 0, 0, 0);
            acc = __builtin_amdgcn_mfma_f32_16x16x32_bf16(qhi, kl, acc, 0, 0, 0);
            acc = __builtin_amdgcn_mfma_f32_16x16x32_bf16(qhi, kh, acc, 0, 0, 0);
            s[f] = acc;
        }

        // ---- online softmax (rows 4g+r, allreduce over 16-lane group) ----
        float pv[4][4];
        #pragma unroll
        for (int r = 0; r < 4; ++r) {
            float mx = fmaxf(fmaxf(s[0][r], s[1][r]), fmaxf(s[2][r], s[3][r]));
            #pragma unroll
            for (int off = 1; off < 16; off <<= 1)
                mx = fmaxf(mx, __shfl_xor(mx, off));
            const float mn = fmaxf(mrow[r], mx);
            const float corr = __expf(mrow[r] - mn);
            mrow[r] = mn;
            float rs = 0.f;
            #pragma unroll
            for (int f = 0; f < 4; ++f) {
                const float p = __expf(s[f][r] - mn);
                pv[f][r] = p;
                rs += p;
            }
            #pragma unroll
            for (int off = 1; off < 16; off <<= 1)
                rs += __shfl_xor(rs, off);
            lrow[r] = lrow[r] * corr + rs;
            o0[r] *= corr;
            o1[r] *= corr;
        }

        // ---- write P (bf16) into this wave's sP slab ----
        #pragma unroll
        for (int f = 0; f < 4; ++f) {
            const int j = c16 + 16 * f;
            #pragma unroll
            for (int r = 0; r < 4; ++r) {
                const int il = 4 * g + r;
                const int poff = 12288 + w * 2048 + il * 128 +
                                 (((j >> 3) + il) & 7) * 16 + (j & 7) * 2;
                *(__bf16*)(sm + poff) = (__bf16)pv[f][r];
            }
        }

        // ---- O += P V ----
        #pragma unroll
        for (int kf = 0; kf < 2; ++kf) {
            const int pc = kf * 4 + g;
            bf16x8 pa = *(bf16x8*)(sm + 12288 + w * 2048 + c16 * 128 +
                                   ((pc + c16) & 7) * 16);
            const int d0 = c16, d1 = 16 + c16;
            bf16x8 vb0 = *(bf16x8*)(sm + 8192 + d0 * 128 + ((pc + d0) & 7) * 16);
            bf16x8 vb1 = *(bf16x8*)(sm + 8192 + d1 * 128 + ((pc + d1) & 7) * 16);
            o0 = __builtin_amdgcn_mfma_f32_16x16x32_bf16(pa, vb0, o0, 0, 0, 0);
            o1 = __builtin_amdgcn_mfma_f32_16x16x32_bf16(pa, vb1, o1, 0, 0, 0);
        }
    }

    // ---- epilogue: normalize, store fp32 [b][h*32+d][n] ----
    #pragma unroll
    for (int r = 0; r < 4; ++r) {
        const float inv = 1.0f / lrow[r];
        const int n = qbase + w * 16 + 4 * g + r;
        aw[((size_t)b * C_IN + h * 32 + c16) * NPIX + n] = o0[r] * inv;
        aw[((size_t)b * C_IN + h * 32 + 16 + c16) * NPIX + n] = o1[r] * inv;
    }
}

// ---------------------------------------------------------------------------
// Kernel C: out[b][o][n] = sum_c W0[o][c] * aw[b][c][n] + b0[o]
// ---------------------------------------------------------------------------
__global__ __launch_bounds__(256) void out_gemm(
    const float* __restrict__ ain, const float* __restrict__ W,
    const float* __restrict__ bias, float* __restrict__ out)
{
    __shared__ float sW[16][68];
    __shared__ float sX[16][68];
    const int b     = blockIdx.z;
    const int oBase = blockIdx.y * 64;
    const int nBase = blockIdx.x * 64;
    const int t = threadIdx.x;
    const int r = t >> 4;
    const int c = t & 15;
    float acc[4][4] = {};
    const float* xb = ain + (size_t)b * C_IN * NPIX;

    for (int kk = 0; kk < C_IN; kk += 16) {
        {
            const int oi = t >> 2;
            const int kj = (t & 3) * 4;
            float4 w4 = *(const float4*)&W[(oBase + oi) * C_IN + kk + kj];
            sW[kj + 0][oi] = w4.x;
            sW[kj + 1][oi] = w4.y;
            sW[kj + 2][oi] = w4.z;
            sW[kj + 3][oi] = w4.w;
            const int kj2 = t >> 4;
            const int ni  = (t & 15) * 4;
            float4 x4 = *(const float4*)&xb[(kk + kj2) * NPIX + nBase + ni];
            *(float4*)&sX[kj2][ni] = x4;
        }
        __syncthreads();
        #pragma unroll
        for (int kj = 0; kj < 16; ++kj) {
            float4 a4 = *(const float4*)&sW[kj][r * 4];
            float4 b4 = *(const float4*)&sX[kj][c * 4];
            float av[4] = {a4.x, a4.y, a4.z, a4.w};
            float bv[4] = {b4.x, b4.y, b4.z, b4.w};
            #pragma unroll
            for (int i = 0; i < 4; ++i)
                #pragma unroll
                for (int j = 0; j < 4; ++j)
                    acc[i][j] += av[i] * bv[j];
        }
        __syncthreads();
    }

    #pragma unroll
    for (int i = 0; i < 4; ++i) {
        const int o = oBase + r * 4 + i;
        const float bi = bias[o];
        float4 st;
        st.x = acc[i][0] + bi;
        st.y = acc[i][1] + bi;
        st.z = acc[i][2] + bi;
        st.w = acc[i][3] + bi;
        *(float4*)&out[((size_t)b * C_IN + o) * NPIX + nBase + c * 4] = st;
    }
}

extern "C" void kernel_launch(void* const* d_in, const int* in_sizes, int n_in,
                              void* d_out, int out_size, void* d_ws, size_t ws_size,
                              hipStream_t stream) {
    const float* x    = (const float*)d_in[0];
    const float* Wqkv = (const float*)d_in[1];
    const float* bqkv = (const float*)d_in[2];
    const float* W0   = (const float*)d_in[3];
    const float* b0   = (const float*)d_in[4];
    float* out = (float*)d_out;

    float* qkvbuf = (float*)d_ws;                       // 4*768*2304 fp32 = 28.3 MB
    float* aw     = qkvbuf + (size_t)4 * 768 * NPIX;    // 4*256*2304 fp32 = 9.4 MB

    qkv_gemm<<<dim3(NPIX / 64, 768 / 64, 4), 256, 0, stream>>>(x, Wqkv, bqkv, qkvbuf);
    attn_mfma<<<dim3(36 * 32), 256, 0, stream>>>(qkvbuf, aw);
    out_gemm<<<dim3(NPIX / 64, C_IN / 64, 4), 256, 0, stream>>>(aw, W0, b0, out);
}

// Round 3
// 231.111 us; speedup vs baseline: 7.3917x; 1.2603x over previous
//
#include <hip/hip_runtime.h>
#include <hip/hip_bf16.h>

#define NPIX 2304
#define C_IN 256
#define NHEADS 8
#define DHEAD 32

typedef float f32x4 __attribute__((ext_vector_type(4)));
typedef __bf16 bf16x8 __attribute__((ext_vector_type(8)));
typedef __bf16 bf16x4 __attribute__((ext_vector_type(4)));

#if __has_builtin(__builtin_amdgcn_exp2f)
#define EXP2F(x) __builtin_amdgcn_exp2f(x)
#else
#define EXP2F(x) exp2f(x)
#endif

__device__ inline void gload_lds16(const void* g, void* l) {
    __builtin_amdgcn_global_load_lds(
        (const __attribute__((address_space(1))) unsigned int*)g,
        (__attribute__((address_space(3))) unsigned int*)l, 16, 0, 0);
}

// ---------------------------------------------------------------------------
// Kernel A: qkv GEMM + scatter epilogue producing attn-ready layouts:
//   q  fp32 [b][h][d][n], pre-scaled by 32^-0.5 * log2(e)
//   khi/klo bf16 [b][h][n][32d], 64B rows, 16B chunks rotate-swizzled:
//       chunk c=d>>3 stored at position (c + (n>>1))&3
//   v  bf16 V^T [b][h][d][n], per-64-key tile rows of 128B, 16B chunks
//       XOR-swizzled: c=(n>>3)&7 stored at position c^(d&7)
// o = d*24 + kq*8 + h
// ---------------------------------------------------------------------------
__global__ __launch_bounds__(256) void qkv_gemm(
    const float* __restrict__ x, const float* __restrict__ W,
    const float* __restrict__ bias, float* __restrict__ qg,
    __bf16* __restrict__ khi, __bf16* __restrict__ klo,
    __bf16* __restrict__ vg)
{
    __shared__ float sW[16][68];
    __shared__ float sX[16][68];
    const int b     = blockIdx.z;
    const int oBase = blockIdx.y * 64;
    const int nBase = blockIdx.x * 64;
    const int t = threadIdx.x;
    const int r = t >> 4;
    const int c = t & 15;
    float acc[4][4] = {};
    const float* xb = x + (size_t)b * C_IN * NPIX;

    for (int kk = 0; kk < C_IN; kk += 16) {
        {
            const int oi = t >> 2;
            const int kj = (t & 3) * 4;
            float4 w4 = *(const float4*)&W[(oBase + oi) * C_IN + kk + kj];
            sW[kj + 0][oi] = w4.x;
            sW[kj + 1][oi] = w4.y;
            sW[kj + 2][oi] = w4.z;
            sW[kj + 3][oi] = w4.w;
            const int kj2 = t >> 4;
            const int ni  = (t & 15) * 4;
            float4 x4 = *(const float4*)&xb[(kk + kj2) * NPIX + nBase + ni];
            *(float4*)&sX[kj2][ni] = x4;
        }
        __syncthreads();
        #pragma unroll
        for (int kj = 0; kj < 16; ++kj) {
            float4 a4 = *(const float4*)&sW[kj][r * 4];
            float4 b4 = *(const float4*)&sX[kj][c * 4];
            float av[4] = {a4.x, a4.y, a4.z, a4.w};
            float bv[4] = {b4.x, b4.y, b4.z, b4.w};
            #pragma unroll
            for (int i = 0; i < 4; ++i)
                #pragma unroll
                for (int j = 0; j < 4; ++j)
                    acc[i][j] += av[i] * bv[j];
        }
        __syncthreads();
    }

    // 32^-0.5 * log2(e): scores computed directly in log2 domain
    const float qscale = 0.17677669529663687f * 1.4426950408889634f;
    #pragma unroll
    for (int i = 0; i < 4; ++i) {
        const int o = oBase + r * 4 + i;
        const float bi = bias[o];
        const int d   = o / 24;
        const int rem = o - d * 24;
        const int kq  = rem >> 3;
        const int h   = rem & 7;
        const int bh  = b * NHEADS + h;
        #pragma unroll
        for (int j = 0; j < 4; ++j) {
            const int n = nBase + c * 4 + j;
            const float val = acc[i][j] + bi;
            if (kq == 0) {
                qg[((size_t)bh * DHEAD + d) * NPIX + n] = val * qscale;
            } else if (kq == 1) {
                __bf16 hb = (__bf16)val;
                __bf16 lb = (__bf16)(val - (float)hb);
                const int cp = ((d >> 3) + (n >> 1)) & 3;
                const size_t off = ((size_t)bh * NPIX + n) * 32 + cp * 8 + (d & 7);
                khi[off] = hb;
                klo[off] = lb;
            } else {
                const int cp = ((n >> 3) & 7) ^ (d & 7);
                vg[((size_t)bh * DHEAD + d) * NPIX + (n >> 6) * 64 + cp * 8 + (n & 7)]
                    = (__bf16)val;
            }
        }
    }
}

// ---------------------------------------------------------------------------
// Kernel B: MFMA flash attention, swapped-operand QK^T, 4 waves x 32 q-rows.
// KV tile 64 keys, double-buffered via global_load_lds (3 issues/wave/tile).
// LDS: [2 bufs x (khi 4K | klo 4K | vT 4K)] + per-wave P^T slab 4K = 40960 B.
// Frag maps (verified r2): A[l&15][(l>>4)*8+e]  B[(l>>4)*8+e][l&15]
//                          D[(l>>4)*4+r][l&15]
// ---------------------------------------------------------------------------
__global__ __launch_bounds__(256) void attn_mfma(
    const float* __restrict__ qg, const __bf16* __restrict__ khi,
    const __bf16* __restrict__ klo, const __bf16* __restrict__ vg,
    float* __restrict__ aw)
{
    __shared__ alignas(16) unsigned char sm[40960];
    const int tid = threadIdx.x;
    const int l   = tid & 63;
    const int w   = tid >> 6;
    const int g   = l >> 4;
    const int c16 = l & 15;

    // bijective XCD swizzle: 576 blocks = 8 XCDs x 72; bh-major logical order
    const int id = blockIdx.x;
    const int lg = (id & 7) * 72 + (id >> 3);
    const int bh = lg / 18;
    const int qt = lg - bh * 18;
    const int b = bh >> 3, h = bh & 7;

    const float*  qb  = qg  + (size_t)bh * DHEAD * NPIX;
    const __bf16* khb = khi + (size_t)bh * NPIX * 32;
    const __bf16* klb = klo + (size_t)bh * NPIX * 32;
    const __bf16* vb  = vg  + (size_t)bh * DHEAD * NPIX;

    const int q0 = qt * 128 + w * 32;       // wave's first q row

    // ---- Q fragments (hi/lo split of pre-scaled q), once per block ----
    bf16x8 qh[2], ql[2];
    #pragma unroll
    for (int qgi = 0; qgi < 2; ++qgi)
        #pragma unroll
        for (int e = 0; e < 8; ++e) {
            float v = qb[(size_t)(g * 8 + e) * NPIX + q0 + qgi * 16 + c16];
            __bf16 hb = (__bf16)v;
            qh[qgi][e] = hb;
            ql[qgi][e] = (__bf16)(v - (float)hb);
        }

    f32x4 o[2][2] = {};                    // [qg][d-half], O^T accumulators
    float m_[2] = {-3e38f, -3e38f};
    float l_[2] = {0.f, 0.f};

    const int vd   = w * 8 + (l >> 3);     // V staging d-row
    const int kswz = (c16 >> 1) & 3;       // K chunk rotate (f-independent)
    unsigned char* const wsl = sm + 24576 + w * 4096;   // P^T slab

    // ---- stage tile kb into buffer buf (3 x global_load_lds per wave) ----
    #define STAGE(buf, kb)                                                     \
    {                                                                          \
        const int j0s = (kb) * 64;                                             \
        unsigned char* lbs = sm + (buf) * 12288;                               \
        gload_lds16(khb + (size_t)(j0s + w * 16) * 32 + l * 8, lbs + w * 1024);\
        gload_lds16(klb + (size_t)(j0s + w * 16) * 32 + l * 8,                 \
                    lbs + 4096 + w * 1024);                                    \
        gload_lds16(vb + (size_t)vd * NPIX + j0s + (l & 7) * 8,                \
                    lbs + 8192 + w * 1024);                                    \
    }

    STAGE(0, 0);
    __syncthreads();

    for (int kb = 0; kb < 36; ++kb) {
        const int buf = kb & 1;
        if (kb + 1 < 36) STAGE(buf ^ 1, kb + 1);
        unsigned char* lb = sm + buf * 12288;

        // ---- S^T = K Q^T (hi/lo: 3 MFMAs), D rows = keys, cols = q ----
        f32x4 sv[2][4];
        #pragma unroll
        for (int f = 0; f < 4; ++f) {
            const int ko = (c16 + 16 * f) * 64 + ((g + kswz) & 3) * 16;
            bf16x8 kh8 = *(bf16x8*)(lb + ko);
            bf16x8 kl8 = *(bf16x8*)(lb + 4096 + ko);
            #pragma unroll
            for (int qgi = 0; qgi < 2; ++qgi) {
                f32x4 acc = {0.f, 0.f, 0.f, 0.f};
                acc = __builtin_amdgcn_mfma_f32_16x16x32_bf16(kh8, ql[qgi], acc, 0, 0, 0);
                acc = __builtin_amdgcn_mfma_f32_16x16x32_bf16(kl8, qh[qgi], acc, 0, 0, 0);
                acc = __builtin_amdgcn_mfma_f32_16x16x32_bf16(kh8, qh[qgi], acc, 0, 0, 0);
                sv[qgi][f] = acc;
            }
        }

        // ---- online softmax (scores already in log2 domain) ----
        #pragma unroll
        for (int qgi = 0; qgi < 2; ++qgi) {
            float mx = fmaxf(fmaxf(sv[qgi][0][0], sv[qgi][0][1]),
                             fmaxf(sv[qgi][0][2], sv[qgi][0][3]));
            #pragma unroll
            for (int f = 1; f < 4; ++f)
                mx = fmaxf(mx, fmaxf(fmaxf(sv[qgi][f][0], sv[qgi][f][1]),
                                     fmaxf(sv[qgi][f][2], sv[qgi][f][3])));
            mx = fmaxf(mx, __shfl_xor(mx, 16));
            mx = fmaxf(mx, __shfl_xor(mx, 32));
            const float mn   = fmaxf(m_[qgi], mx);
            const float corr = EXP2F(m_[qgi] - mn);
            m_[qgi] = mn;
            float rs = 0.f;
            __bf16 pb[16];
            #pragma unroll
            for (int f = 0; f < 4; ++f)
                #pragma unroll
                for (int rr = 0; rr < 4; ++rr) {
                    const float p = EXP2F(sv[qgi][f][rr] - mn);
                    rs += p;
                    pb[f * 4 + rr] = (__bf16)p;
                }
            rs += __shfl_xor(rs, 16);
            rs += __shfl_xor(rs, 32);
            l_[qgi] = l_[qgi] * corr + rs;
            o[qgi][0] *= corr;
            o[qgi][1] *= corr;
            // P^T[q][key] (XOR-swizzled 16B chunks), b64 packed writes
            const int qrow = qgi * 16 + c16;
            #pragma unroll
            for (int f = 0; f < 4; ++f) {
                const int ch = (2 * f + (g >> 1)) ^ (c16 & 7);
                *(bf16x4*)(wsl + qrow * 128 + ch * 16 + (g & 1) * 8) =
                    *(bf16x4*)&pb[f * 4];
            }
        }

        // ---- O^T += V^T P  (A = V^T from LDS, B = P^T rows) ----
        #pragma unroll
        for (int kc = 0; kc < 2; ++kc) {
            const int vch = (((g + 4 * kc) ^ (c16 & 7))) * 16;
            bf16x8 va0 = *(bf16x8*)(lb + 8192 + c16 * 128 + vch);
            bf16x8 va1 = *(bf16x8*)(lb + 8192 + (16 + c16) * 128 + vch);
            #pragma unroll
            for (int qgi = 0; qgi < 2; ++qgi) {
                bf16x8 pf = *(bf16x8*)(wsl + (qgi * 16 + c16) * 128 + vch);
                o[qgi][0] = __builtin_amdgcn_mfma_f32_16x16x32_bf16(va0, pf, o[qgi][0], 0, 0, 0);
                o[qgi][1] = __builtin_amdgcn_mfma_f32_16x16x32_bf16(va1, pf, o[qgi][1], 0, 0, 0);
            }
        }

        __syncthreads();   // drains vmcnt (prefetch) + lgkm, flips buffer
    }

    // ---- epilogue: normalize, store O^T rows d' = 4g+r (+16) ----
    #pragma unroll
    for (int qgi = 0; qgi < 2; ++qgi) {
        const float inv = 1.0f / l_[qgi];
        const int n = qt * 128 + w * 32 + qgi * 16 + c16;
        #pragma unroll
        for (int rr = 0; rr < 4; ++rr) {
            aw[((size_t)b * C_IN + h * 32 + 4 * g + rr) * NPIX + n]      = o[qgi][0][rr] * inv;
            aw[((size_t)b * C_IN + h * 32 + 16 + 4 * g + rr) * NPIX + n] = o[qgi][1][rr] * inv;
        }
    }
}

// ---------------------------------------------------------------------------
// Kernel C: out[b][o][n] = sum_c W0[o][c] * aw[b][c][n] + b0[o]
// ---------------------------------------------------------------------------
__global__ __launch_bounds__(256) void out_gemm(
    const float* __restrict__ ain, const float* __restrict__ W,
    const float* __restrict__ bias, float* __restrict__ out)
{
    __shared__ float sW[16][68];
    __shared__ float sX[16][68];
    const int b     = blockIdx.z;
    const int oBase = blockIdx.y * 64;
    const int nBase = blockIdx.x * 64;
    const int t = threadIdx.x;
    const int r = t >> 4;
    const int c = t & 15;
    float acc[4][4] = {};
    const float* xb = ain + (size_t)b * C_IN * NPIX;

    for (int kk = 0; kk < C_IN; kk += 16) {
        {
            const int oi = t >> 2;
            const int kj = (t & 3) * 4;
            float4 w4 = *(const float4*)&W[(oBase + oi) * C_IN + kk + kj];
            sW[kj + 0][oi] = w4.x;
            sW[kj + 1][oi] = w4.y;
            sW[kj + 2][oi] = w4.z;
            sW[kj + 3][oi] = w4.w;
            const int kj2 = t >> 4;
            const int ni  = (t & 15) * 4;
            float4 x4 = *(const float4*)&xb[(kk + kj2) * NPIX + nBase + ni];
            *(float4*)&sX[kj2][ni] = x4;
        }
        __syncthreads();
        #pragma unroll
        for (int kj = 0; kj < 16; ++kj) {
            float4 a4 = *(const float4*)&sW[kj][r * 4];
            float4 b4 = *(const float4*)&sX[kj][c * 4];
            float av[4] = {a4.x, a4.y, a4.z, a4.w};
            float bv[4] = {b4.x, b4.y, b4.z, b4.w};
            #pragma unroll
            for (int i = 0; i < 4; ++i)
                #pragma unroll
                for (int j = 0; j < 4; ++j)
                    acc[i][j] += av[i] * bv[j];
        }
        __syncthreads();
    }

    #pragma unroll
    for (int i = 0; i < 4; ++i) {
        const int o = oBase + r * 4 + i;
        const float bi = bias[o];
        float4 st;
        st.x = acc[i][0] + bi;
        st.y = acc[i][1] + bi;
        st.z = acc[i][2] + bi;
        st.w = acc[i][3] + bi;
        *(float4*)&out[((size_t)b * C_IN + o) * NPIX + nBase + c * 4] = st;
    }
}

extern "C" void kernel_launch(void* const* d_in, const int* in_sizes, int n_in,
                              void* d_out, int out_size, void* d_ws, size_t ws_size,
                              hipStream_t stream) {
    const float* x    = (const float*)d_in[0];
    const float* Wqkv = (const float*)d_in[1];
    const float* bqkv = (const float*)d_in[2];
    const float* W0   = (const float*)d_in[3];
    const float* b0   = (const float*)d_in[4];
    float* out = (float*)d_out;

    const size_t per = (size_t)4 * NHEADS * DHEAD * NPIX;  // 2,359,296 elements
    float*  qg  = (float*)d_ws;                 // fp32, 9.44 MB
    __bf16* khi = (__bf16*)(qg + per);          // bf16, 4.72 MB
    __bf16* klo = khi + per;
    __bf16* vg  = klo + per;
    float*  aw  = (float*)(vg + per);           // fp32, 9.44 MB
                                                // total 33.0 MB

    qkv_gemm<<<dim3(NPIX / 64, 768 / 64, 4), 256, 0, stream>>>(
        x, Wqkv, bqkv, qg, khi, klo, vg);
    attn_mfma<<<dim3(18 * 32), 256, 0, stream>>>(qg, khi, klo, vg, aw);
    out_gemm<<<dim3(NPIX / 64, C_IN / 64, 4), 256, 0, stream>>>(aw, W0, b0, out);
}

// Round 4
// 213.186 us; speedup vs baseline: 8.0132x; 1.0841x over previous
//
#include <hip/hip_runtime.h>
#include <hip/hip_bf16.h>

#define NPIX 2304
#define C_IN 256
#define NHEADS 8
#define DHEAD 32

typedef float f32x4 __attribute__((ext_vector_type(4)));
typedef __bf16 bf16x8 __attribute__((ext_vector_type(8)));
typedef __bf16 bf16x4 __attribute__((ext_vector_type(4)));

#if __has_builtin(__builtin_amdgcn_exp2f)
#define EXP2F(x) __builtin_amdgcn_exp2f(x)
#else
#define EXP2F(x) exp2f(x)
#endif

__device__ inline void gload_lds16(const void* g, void* l) {
    __builtin_amdgcn_global_load_lds(
        (const __attribute__((address_space(1))) unsigned int*)g,
        (__attribute__((address_space(3))) unsigned int*)l, 16, 0, 0);
}

// ---------------------------------------------------------------------------
// prep_w: Wqkv [768x256] and W0 [256x256] fp32 -> hi/lo bf16 (same layout).
// ---------------------------------------------------------------------------
__global__ __launch_bounds__(256) void prep_w(
    const float* __restrict__ Wq, const float* __restrict__ W0,
    __bf16* __restrict__ whi, __bf16* __restrict__ wlo,
    __bf16* __restrict__ w0h, __bf16* __restrict__ w0l)
{
    const int e4 = blockIdx.x * 256 + threadIdx.x;   // 0..65535
    const int el = e4 * 4;
    float4 v;
    __bf16 *ph, *pl;
    if (el < 196608) {
        v = *(const float4*)&Wq[el];
        ph = whi + el; pl = wlo + el;
    } else {
        v = *(const float4*)&W0[el - 196608];
        ph = w0h + (el - 196608); pl = w0l + (el - 196608);
    }
    float a[4] = {v.x, v.y, v.z, v.w};
    bf16x4 hv, lv;
    #pragma unroll
    for (int i = 0; i < 4; ++i) {
        __bf16 hb = (__bf16)a[i];
        hv[i] = hb;
        lv[i] = (__bf16)(a[i] - (float)hb);
    }
    *(bf16x4*)ph = hv;
    *(bf16x4*)pl = lv;
}

// ---------------------------------------------------------------------------
// prep_x: x fp32 [b][256c][2304n] -> xth/xtl bf16 [b][2304n][256c] (transpose
// + hi/lo split).  64x64 tile via LDS (u32-packed hi|lo), pad 69 u32/row.
// ---------------------------------------------------------------------------
__global__ __launch_bounds__(256) void prep_x(
    const float* __restrict__ x,
    __bf16* __restrict__ xth, __bf16* __restrict__ xtl)
{
    __shared__ unsigned int lds[64 * 69];
    const int t  = threadIdx.x;
    const int n0 = blockIdx.x * 64;
    const int c0 = blockIdx.y * 64;
    const int b  = blockIdx.z;
    const float* xb = x + (size_t)b * C_IN * NPIX;

    // phase 1: read rows (c), pack (hi<<16)|lo into lds[c][n]
    #pragma unroll
    for (int p = 0; p < 4; ++p) {
        const int r    = (t >> 4) + p * 16;
        const int ncol = (t & 15) * 4;
        float4 v = *(const float4*)&xb[(size_t)(c0 + r) * NPIX + n0 + ncol];
        float a[4] = {v.x, v.y, v.z, v.w};
        #pragma unroll
        for (int i = 0; i < 4; ++i) {
            __bf16 hb = (__bf16)a[i];
            __bf16 lb = (__bf16)(a[i] - (float)hb);
            unsigned int u = ((unsigned int)__builtin_bit_cast(unsigned short, hb) << 16)
                           | __builtin_bit_cast(unsigned short, lb);
            lds[r * 69 + ncol + i] = u;
        }
    }
    __syncthreads();

    // phase 2: write rows (n), 8 consecutive c per thread
    #pragma unroll
    for (int p = 0; p < 2; ++p) {
        const int nn = (t >> 3) + p * 32;
        const int ch = t & 7;
        bf16x8 h8, l8;
        #pragma unroll
        for (int i = 0; i < 8; ++i) {
            unsigned int u = lds[(ch * 8 + i) * 69 + nn];
            h8[i] = __builtin_bit_cast(__bf16, (unsigned short)(u >> 16));
            l8[i] = __builtin_bit_cast(__bf16, (unsigned short)(u & 0xffffu));
        }
        const size_t off = ((size_t)b * NPIX + n0 + nn) * 256 + c0 + ch * 8;
        *(bf16x8*)&xth[off] = h8;
        *(bf16x8*)&xtl[off] = l8;
    }
}

// ---------------------------------------------------------------------------
// qkv_mfma: qkv[o][n] = Wqkv[o][:] . x[:][n] + bias, hi/lo 3-MFMA split.
// blockIdx.y -> (kq, d0): block owns o-rows {24*(d0+dd)+8*kq+h}.
// Scatter epilogue -> qg fp32 [bh][d][n] (pre-scaled), khi/klo swizzled,
// vg swizzled (same layouts as round 3).
// LDS: 2 bufs x (Ahi|Alo|Bhi|Blo, each [4 chunk][64 row][16B]) = 32 KiB.
// ---------------------------------------------------------------------------
__global__ __launch_bounds__(256) void qkv_mfma(
    const __bf16* __restrict__ whi, const __bf16* __restrict__ wlo,
    const __bf16* __restrict__ xth, const __bf16* __restrict__ xtl,
    const float* __restrict__ bias, float* __restrict__ qg,
    __bf16* __restrict__ khi, __bf16* __restrict__ klo,
    __bf16* __restrict__ vg)
{
    __shared__ alignas(16) unsigned char sm[32768];
    const int tid = threadIdx.x;
    const int l   = tid & 63;
    const int w   = tid >> 6;
    const int g   = l >> 4;
    const int c16 = l & 15;
    const int n0  = blockIdx.x * 64;
    const int y   = blockIdx.y;
    const int kq  = y >> 2;
    const int d0  = (y & 3) * 8;
    const int b   = blockIdx.z;
    const int olane = 24 * (d0 + (l >> 3)) + 8 * kq + (l & 7);
    const size_t xrow = (size_t)b * NPIX + n0;

    const int wo = (w >> 1) * 32;
    const int wn = (w & 1) * 32;
    f32x4 acc[2][2] = {};

#define STAGEQ(buf, ks)                                                        \
    {                                                                          \
        unsigned char* lbs = sm + (buf) * 16384;                               \
        const int co = (ks) * 32 + w * 8;                                      \
        gload_lds16(whi + (size_t)olane * 256 + co, lbs + w * 1024);           \
        gload_lds16(wlo + (size_t)olane * 256 + co, lbs + 4096 + w * 1024);    \
        gload_lds16(xth + (xrow + l) * 256 + co, lbs + 8192 + w * 1024);       \
        gload_lds16(xtl + (xrow + l) * 256 + co, lbs + 12288 + w * 1024);      \
    }

    STAGEQ(0, 0);
    __syncthreads();
    for (int ks = 0; ks < 8; ++ks) {
        const int buf = ks & 1;
        if (ks + 1 < 8) STAGEQ(buf ^ 1, ks + 1);
        unsigned char* lb = sm + buf * 16384;
        bf16x8 ah[2], al[2], bh8[2], bl8[2];
        #pragma unroll
        for (int oi = 0; oi < 2; ++oi) {
            const int ra = (g * 64 + wo + oi * 16 + c16) * 16;
            ah[oi] = *(bf16x8*)(lb + ra);
            al[oi] = *(bf16x8*)(lb + 4096 + ra);
        }
        #pragma unroll
        for (int ni = 0; ni < 2; ++ni) {
            const int rb = (g * 64 + wn + ni * 16 + c16) * 16;
            bh8[ni] = *(bf16x8*)(lb + 8192 + rb);
            bl8[ni] = *(bf16x8*)(lb + 12288 + rb);
        }
        #pragma unroll
        for (int oi = 0; oi < 2; ++oi)
            #pragma unroll
            for (int ni = 0; ni < 2; ++ni) {
                acc[oi][ni] = __builtin_amdgcn_mfma_f32_16x16x32_bf16(al[oi], bh8[ni], acc[oi][ni], 0, 0, 0);
                acc[oi][ni] = __builtin_amdgcn_mfma_f32_16x16x32_bf16(ah[oi], bl8[ni], acc[oi][ni], 0, 0, 0);
                acc[oi][ni] = __builtin_amdgcn_mfma_f32_16x16x32_bf16(ah[oi], bh8[ni], acc[oi][ni], 0, 0, 0);
            }
        __syncthreads();
    }
#undef STAGEQ

    const float qscale = 0.17677669529663687f * 1.4426950408889634f;
    #pragma unroll
    for (int oi = 0; oi < 2; ++oi) {
        #pragma unroll
        for (int rr = 0; rr < 4; ++rr) {
            const int ri = wo + oi * 16 + 4 * g + rr;
            const int d  = d0 + (ri >> 3);
            const int h  = ri & 7;
            const int o  = 24 * d + 8 * kq + h;
            const float bi = bias[o];
            const int bh_ = b * NHEADS + h;
            #pragma unroll
            for (int ni = 0; ni < 2; ++ni) {
                const int n = n0 + wn + ni * 16 + c16;
                const float val = acc[oi][ni][rr] + bi;
                if (kq == 0) {
                    qg[((size_t)bh_ * DHEAD + d) * NPIX + n] = val * qscale;
                } else if (kq == 1) {
                    __bf16 hb = (__bf16)val;
                    __bf16 lo = (__bf16)(val - (float)hb);
                    const int cp = ((d >> 3) + (n >> 1)) & 3;
                    const size_t off = ((size_t)bh_ * NPIX + n) * 32 + cp * 8 + (d & 7);
                    khi[off] = hb;
                    klo[off] = lo;
                } else {
                    const int cp = ((n >> 3) & 7) ^ (d & 7);
                    vg[((size_t)bh_ * DHEAD + d) * NPIX + (n >> 6) * 64 + cp * 8 + (n & 7)]
                        = (__bf16)val;
                }
            }
        }
    }
}

// ---------------------------------------------------------------------------
// attn_mfma: as round 3 (swapped QK^T, 4 waves x 32 q, dbuf gload staging)
// + setprio around MFMA clusters, defer-max (THR=8, wave-uniform __all),
// epilogue writes aw^T hi/lo bf16 [b][n][256c] for the MFMA out-projection.
// ---------------------------------------------------------------------------
__global__ __launch_bounds__(256) void attn_mfma(
    const float* __restrict__ qg, const __bf16* __restrict__ khi,
    const __bf16* __restrict__ klo, const __bf16* __restrict__ vg,
    __bf16* __restrict__ awh, __bf16* __restrict__ awl)
{
    __shared__ alignas(16) unsigned char sm[40960];
    const int tid = threadIdx.x;
    const int l   = tid & 63;
    const int w   = tid >> 6;
    const int g   = l >> 4;
    const int c16 = l & 15;

    const int id = blockIdx.x;
    const int lg = (id & 7) * 72 + (id >> 3);
    const int bh = lg / 18;
    const int qt = lg - bh * 18;
    const int b = bh >> 3, h = bh & 7;

    const float*  qb  = qg  + (size_t)bh * DHEAD * NPIX;
    const __bf16* khb = khi + (size_t)bh * NPIX * 32;
    const __bf16* klb = klo + (size_t)bh * NPIX * 32;
    const __bf16* vb  = vg  + (size_t)bh * DHEAD * NPIX;

    const int q0 = qt * 128 + w * 32;

    bf16x8 qh[2], ql[2];
    #pragma unroll
    for (int qgi = 0; qgi < 2; ++qgi)
        #pragma unroll
        for (int e = 0; e < 8; ++e) {
            float v = qb[(size_t)(g * 8 + e) * NPIX + q0 + qgi * 16 + c16];
            __bf16 hb = (__bf16)v;
            qh[qgi][e] = hb;
            ql[qgi][e] = (__bf16)(v - (float)hb);
        }

    f32x4 o[2][2] = {};
    float m_[2] = {-3e38f, -3e38f};
    float l_[2] = {0.f, 0.f};

    const int vd   = w * 8 + (l >> 3);
    const int kswz = (c16 >> 1) & 3;
    unsigned char* const wsl = sm + 24576 + w * 4096;

#define STAGE(buf, kb)                                                         \
    {                                                                          \
        const int j0s = (kb) * 64;                                             \
        unsigned char* lbs = sm + (buf) * 12288;                               \
        gload_lds16(khb + (size_t)(j0s + w * 16) * 32 + l * 8, lbs + w * 1024);\
        gload_lds16(klb + (size_t)(j0s + w * 16) * 32 + l * 8,                 \
                    lbs + 4096 + w * 1024);                                    \
        gload_lds16(vb + (size_t)vd * NPIX + j0s + (l & 7) * 8,                \
                    lbs + 8192 + w * 1024);                                    \
    }

    STAGE(0, 0);
    __syncthreads();

    for (int kb = 0; kb < 36; ++kb) {
        const int buf = kb & 1;
        if (kb + 1 < 36) STAGE(buf ^ 1, kb + 1);
        unsigned char* lb = sm + buf * 12288;

        f32x4 sv[2][4];
        __builtin_amdgcn_s_setprio(1);
        #pragma unroll
        for (int f = 0; f < 4; ++f) {
            const int ko = (c16 + 16 * f) * 64 + ((g + kswz) & 3) * 16;
            bf16x8 kh8 = *(bf16x8*)(lb + ko);
            bf16x8 kl8 = *(bf16x8*)(lb + 4096 + ko);
            #pragma unroll
            for (int qgi = 0; qgi < 2; ++qgi) {
                f32x4 acc = {0.f, 0.f, 0.f, 0.f};
                acc = __builtin_amdgcn_mfma_f32_16x16x32_bf16(kh8, ql[qgi], acc, 0, 0, 0);
                acc = __builtin_amdgcn_mfma_f32_16x16x32_bf16(kl8, qh[qgi], acc, 0, 0, 0);
                acc = __builtin_amdgcn_mfma_f32_16x16x32_bf16(kh8, qh[qgi], acc, 0, 0, 0);
                sv[qgi][f] = acc;
            }
        }
        __builtin_amdgcn_s_setprio(0);

        #pragma unroll
        for (int qgi = 0; qgi < 2; ++qgi) {
            float mx = fmaxf(fmaxf(sv[qgi][0][0], sv[qgi][0][1]),
                             fmaxf(sv[qgi][0][2], sv[qgi][0][3]));
            #pragma unroll
            for (int f = 1; f < 4; ++f)
                mx = fmaxf(mx, fmaxf(fmaxf(sv[qgi][f][0], sv[qgi][f][1]),
                                     fmaxf(sv[qgi][f][2], sv[qgi][f][3])));
            mx = fmaxf(mx, __shfl_xor(mx, 16));
            mx = fmaxf(mx, __shfl_xor(mx, 32));
            float mn = m_[qgi];
            if (!__all(mx <= mn + 8.0f)) {          // defer-max (THR=8, log2)
                mn = fmaxf(mn, mx);
                const float corr = EXP2F(m_[qgi] - mn);
                m_[qgi] = mn;
                l_[qgi] *= corr;
                o[qgi][0] *= corr;
                o[qgi][1] *= corr;
            }
            float rs = 0.f;
            __bf16 pb[16];
            #pragma unroll
            for (int f = 0; f < 4; ++f)
                #pragma unroll
                for (int rr = 0; rr < 4; ++rr) {
                    const float p = EXP2F(sv[qgi][f][rr] - mn);
                    rs += p;
                    pb[f * 4 + rr] = (__bf16)p;
                }
            rs += __shfl_xor(rs, 16);
            rs += __shfl_xor(rs, 32);
            l_[qgi] += rs;
            const int qrow = qgi * 16 + c16;
            #pragma unroll
            for (int f = 0; f < 4; ++f) {
                const int ch = (2 * f + (g >> 1)) ^ (c16 & 7);
                *(bf16x4*)(wsl + qrow * 128 + ch * 16 + (g & 1) * 8) =
                    *(bf16x4*)&pb[f * 4];
            }
        }

        __builtin_amdgcn_s_setprio(1);
        #pragma unroll
        for (int kc = 0; kc < 2; ++kc) {
            const int vch = (((g + 4 * kc) ^ (c16 & 7))) * 16;
            bf16x8 va0 = *(bf16x8*)(lb + 8192 + c16 * 128 + vch);
            bf16x8 va1 = *(bf16x8*)(lb + 8192 + (16 + c16) * 128 + vch);
            #pragma unroll
            for (int qgi = 0; qgi < 2; ++qgi) {
                bf16x8 pf = *(bf16x8*)(wsl + (qgi * 16 + c16) * 128 + vch);
                o[qgi][0] = __builtin_amdgcn_mfma_f32_16x16x32_bf16(va0, pf, o[qgi][0], 0, 0, 0);
                o[qgi][1] = __builtin_amdgcn_mfma_f32_16x16x32_bf16(va1, pf, o[qgi][1], 0, 0, 0);
            }
        }
        __builtin_amdgcn_s_setprio(0);

        __syncthreads();
    }
#undef STAGE

    // epilogue: aw^T hi/lo bf16 [b][n][256c], c = h*32 + dh*16 + 4g + rr
    #pragma unroll
    for (int qgi = 0; qgi < 2; ++qgi) {
        const float inv = 1.0f / l_[qgi];
        const int n = q0 + qgi * 16 + c16;
        const size_t rb = ((size_t)b * NPIX + n) * 256 + h * 32;
        #pragma unroll
        for (int dh = 0; dh < 2; ++dh) {
            bf16x4 hv, lv;
            #pragma unroll
            for (int rr = 0; rr < 4; ++rr) {
                const float val = o[qgi][dh][rr] * inv;
                __bf16 hb = (__bf16)val;
                hv[rr] = hb;
                lv[rr] = (__bf16)(val - (float)hb);
            }
            *(bf16x4*)&awh[rb + dh * 16 + 4 * g] = hv;
            *(bf16x4*)&awl[rb + dh * 16 + 4 * g] = lv;
        }
    }
}

// ---------------------------------------------------------------------------
// out_mfma: out[o][n] = W0[o][:] . aw[:][n] + b0, hi/lo 3-MFMA split.
// Natural o-rows; fp32 coalesced stores.
// ---------------------------------------------------------------------------
__global__ __launch_bounds__(256) void out_mfma(
    const __bf16* __restrict__ w0h, const __bf16* __restrict__ w0l,
    const __bf16* __restrict__ awh, const __bf16* __restrict__ awl,
    const float* __restrict__ bias, float* __restrict__ out)
{
    __shared__ alignas(16) unsigned char sm[32768];
    const int tid = threadIdx.x;
    const int l   = tid & 63;
    const int w   = tid >> 6;
    const int g   = l >> 4;
    const int c16 = l & 15;
    const int n0  = blockIdx.x * 64;
    const int o0  = blockIdx.y * 64;
    const int b   = blockIdx.z;
    const size_t arow = (size_t)b * NPIX + n0;

    const int wo = (w >> 1) * 32;
    const int wn = (w & 1) * 32;
    f32x4 acc[2][2] = {};

#define STAGEO(buf, ks)                                                        \
    {                                                                          \
        unsigned char* lbs = sm + (buf) * 16384;                               \
        const int co = (ks) * 32 + w * 8;                                      \
        gload_lds16(w0h + (size_t)(o0 + l) * 256 + co, lbs + w * 1024);        \
        gload_lds16(w0l + (size_t)(o0 + l) * 256 + co, lbs + 4096 + w * 1024); \
        gload_lds16(awh + (arow + l) * 256 + co, lbs + 8192 + w * 1024);       \
        gload_lds16(awl + (arow + l) * 256 + co, lbs + 12288 + w * 1024);      \
    }

    STAGEO(0, 0);
    __syncthreads();
    for (int ks = 0; ks < 8; ++ks) {
        const int buf = ks & 1;
        if (ks + 1 < 8) STAGEO(buf ^ 1, ks + 1);
        unsigned char* lb = sm + buf * 16384;
        bf16x8 ah[2], al[2], bh8[2], bl8[2];
        #pragma unroll
        for (int oi = 0; oi < 2; ++oi) {
            const int ra = (g * 64 + wo + oi * 16 + c16) * 16;
            ah[oi] = *(bf16x8*)(lb + ra);
            al[oi] = *(bf16x8*)(lb + 4096 + ra);
        }
        #pragma unroll
        for (int ni = 0; ni < 2; ++ni) {
            const int rb = (g * 64 + wn + ni * 16 + c16) * 16;
            bh8[ni] = *(bf16x8*)(lb + 8192 + rb);
            bl8[ni] = *(bf16x8*)(lb + 12288 + rb);
        }
        #pragma unroll
        for (int oi = 0; oi < 2; ++oi)
            #pragma unroll
            for (int ni = 0; ni < 2; ++ni) {
                acc[oi][ni] = __builtin_amdgcn_mfma_f32_16x16x32_bf16(al[oi], bh8[ni], acc[oi][ni], 0, 0, 0);
                acc[oi][ni] = __builtin_amdgcn_mfma_f32_16x16x32_bf16(ah[oi], bl8[ni], acc[oi][ni], 0, 0, 0);
                acc[oi][ni] = __builtin_amdgcn_mfma_f32_16x16x32_bf16(ah[oi], bh8[ni], acc[oi][ni], 0, 0, 0);
            }
        __syncthreads();
    }
#undef STAGEO

    #pragma unroll
    for (int oi = 0; oi < 2; ++oi) {
        #pragma unroll
        for (int rr = 0; rr < 4; ++rr) {
            const int o = o0 + wo + oi * 16 + 4 * g + rr;
            const float bi = bias[o];
            #pragma unroll
            for (int ni = 0; ni < 2; ++ni) {
                const int n = n0 + wn + ni * 16 + c16;
                out[((size_t)b * C_IN + o) * NPIX + n] = acc[oi][ni][rr] + bi;
            }
        }
    }
}

extern "C" void kernel_launch(void* const* d_in, const int* in_sizes, int n_in,
                              void* d_out, int out_size, void* d_ws, size_t ws_size,
                              hipStream_t stream) {
    const float* x    = (const float*)d_in[0];
    const float* Wqkv = (const float*)d_in[1];
    const float* bqkv = (const float*)d_in[2];
    const float* W0   = (const float*)d_in[3];
    const float* b0   = (const float*)d_in[4];
    float* out = (float*)d_out;

    char* ws = (char*)d_ws;
    __bf16* xth = (__bf16*)(ws);                    // 4,718,592 B
    __bf16* xtl = (__bf16*)(ws + 4718592);
    float*  qg  = (float*) (ws + 9437184);          // 9,437,184 B
    __bf16* khi = (__bf16*)(ws + 18874368);
    __bf16* klo = (__bf16*)(ws + 23592960);
    __bf16* vg  = (__bf16*)(ws + 28311552);
    __bf16* whi = (__bf16*)(ws + 33030144);         // 393,216 B
    __bf16* wlo = (__bf16*)(ws + 33423360);
    __bf16* w0h = (__bf16*)(ws + 33816576);         // 131,072 B
    __bf16* w0l = (__bf16*)(ws + 33947648);
    // total 34,078,720 B; aw aliases xt (disjoint lifetimes)
    __bf16* awh = xth;
    __bf16* awl = xtl;

    prep_w<<<256, 256, 0, stream>>>(Wqkv, W0, whi, wlo, w0h, w0l);
    prep_x<<<dim3(NPIX / 64, C_IN / 64, 4), 256, 0, stream>>>(x, xth, xtl);
    qkv_mfma<<<dim3(NPIX / 64, 12, 4), 256, 0, stream>>>(
        whi, wlo, xth, xtl, bqkv, qg, khi, klo, vg);
    attn_mfma<<<dim3(18 * 32), 256, 0, stream>>>(qg, khi, klo, vg, awh, awl);
    out_mfma<<<dim3(NPIX / 64, C_IN / 64, 4), 256, 0, stream>>>(
        w0h, w0l, awh, awl, b0, out);
}